// Round 8
// baseline (468.699 us; speedup 1.0000x reference)
//
#include <hip/hip_runtime.h>

#define EMB   1024
#define HEADS 16
#define HDIM  64
#define BATCH 2
#define SEQ   2048
#define MROWS (BATCH*SEQ)   // 4096
#define QSCALE 0.1803368801111204f   // 0.125 * log2(e): Q pre-scale -> exp2 softmax

typedef __attribute__((ext_vector_type(8))) short bf16x8;   // 8 bf16 (4 VGPRs)
typedef __attribute__((ext_vector_type(4))) float f32x4;    // MFMA C/D
typedef unsigned short u16;

__device__ __forceinline__ u16 f2bf(float f) {              // round-to-nearest-even
    unsigned u = __float_as_uint(f);
    u += 0x7fffu + ((u >> 16) & 1u);
    return (u16)(u >> 16);
}
__device__ __forceinline__ float bf2f(u16 h) {
    return __uint_as_float((unsigned)h << 16);
}
__device__ __forceinline__ float fast_exp2(float x) {
#if __has_builtin(__builtin_amdgcn_exp2f)
    return __builtin_amdgcn_exp2f(x);
#else
    return __expf(x * 0.6931471805599453f);
#endif
}
// pack two floats -> two truncated bf16 in one v_perm_b32 (lo in [15:0])
__device__ __forceinline__ unsigned pk_trunc(float lo, float hi) {
    return __builtin_amdgcn_perm(__float_as_uint(hi), __float_as_uint(lo),
                                 0x07060302u);
}

// XOR-swizzled LDS offset (u16 units): 64-u16 rows, 8-u16 chunks, chunk^=row&7.
#define SWZ(r, ch) ((((r) << 6)) + ((((ch) ^ ((r) & 7))) << 3))

// ---------------------------------------------------------------------------
// prep1: fused  [bx<2048] X->Xh/Xl split  |  [else] Wq/Wk transpose+hi/lo.
// ---------------------------------------------------------------------------
__global__ __launch_bounds__(256)
void prep1(const float* __restrict__ X, const float* __restrict__ Wq,
           const float* __restrict__ Wk,
           u16* __restrict__ Xh, u16* __restrict__ Xl,
           u16* __restrict__ Qth, u16* __restrict__ Qtl,
           u16* __restrict__ Kth, u16* __restrict__ Ktl)
{
    const int bx = blockIdx.x;
    if (bx < 2048) {                       // xsplit: 8 elems/thread
        int i = (bx * 256 + threadIdx.x) * 8;
#pragma unroll
        for (int half = 0; half < 2; ++half) {
            float4 v = *(const float4*)(X + i + half * 4);
            ushort4 hi, lo;
            hi.x = f2bf(v.x); lo.x = f2bf(v.x - bf2f(hi.x));
            hi.y = f2bf(v.y); lo.y = f2bf(v.y - bf2f(hi.y));
            hi.z = f2bf(v.z); lo.z = f2bf(v.z - bf2f(hi.z));
            hi.w = f2bf(v.w); lo.w = f2bf(v.w - bf2f(hi.w));
            *(ushort4*)(Xh + i + half * 4) = hi;
            *(ushort4*)(Xl + i + half * 4) = lo;
        }
    } else {                               // wtrans: [16][1024][64] -> [h*64+d][e]
        const int f = bx - 2048;           // 0..1023
        const int z = f >> 9, y = (f >> 5) & 15, x = f & 31;
        const float* W  = z ? Wk  : Wq;
        u16* Oh         = z ? Kth : Qth;
        u16* Ol         = z ? Ktl : Qtl;
        const int d  = threadIdx.x & 63;
        const int e0 = (x * 4 + (threadIdx.x >> 6)) * 8;
        const float* src = W + ((size_t)y * EMB + e0) * HDIM + d;
        ushort4 h0, h1, l0, l1;
        float v; u16 hv;
        v = src[0 * 64]; hv = f2bf(v); h0.x = hv; l0.x = f2bf(v - bf2f(hv));
        v = src[1 * 64]; hv = f2bf(v); h0.y = hv; l0.y = f2bf(v - bf2f(hv));
        v = src[2 * 64]; hv = f2bf(v); h0.z = hv; l0.z = f2bf(v - bf2f(hv));
        v = src[3 * 64]; hv = f2bf(v); h0.w = hv; l0.w = f2bf(v - bf2f(hv));
        v = src[4 * 64]; hv = f2bf(v); h1.x = hv; l1.x = f2bf(v - bf2f(hv));
        v = src[5 * 64]; hv = f2bf(v); h1.y = hv; l1.y = f2bf(v - bf2f(hv));
        v = src[6 * 64]; hv = f2bf(v); h1.z = hv; l1.z = f2bf(v - bf2f(hv));
        v = src[7 * 64]; hv = f2bf(v); h1.w = hv; l1.w = f2bf(v - bf2f(hv));
        size_t obase = ((size_t)y * HDIM + d) * EMB + e0;
        *(ushort4*)(Oh + obase)     = h0;
        *(ushort4*)(Oh + obase + 4) = h1;
        *(ushort4*)(Ol + obase)     = l0;
        *(ushort4*)(Ol + obase + 4) = l1;
    }
}

// ---------------------------------------------------------------------------
// prep2 (after qkv_z01): [f<512] Wv transpose->bf16  |  [else] Wo -> bf16.
// ---------------------------------------------------------------------------
__global__ __launch_bounds__(256)
void prep2(const float* __restrict__ Wv, const float* __restrict__ Wo,
           u16* __restrict__ Vth, u16* __restrict__ Woh)
{
    const int f = blockIdx.x;
    if (f < 512) {
        const int y = f >> 5, x = f & 31;
        const int d  = threadIdx.x & 63;
        const int e0 = (x * 4 + (threadIdx.x >> 6)) * 8;
        const float* src = Wv + ((size_t)y * EMB + e0) * HDIM + d;
        ushort4 h0, h1;
        h0.x = f2bf(src[0 * 64]); h0.y = f2bf(src[1 * 64]);
        h0.z = f2bf(src[2 * 64]); h0.w = f2bf(src[3 * 64]);
        h1.x = f2bf(src[4 * 64]); h1.y = f2bf(src[5 * 64]);
        h1.z = f2bf(src[6 * 64]); h1.w = f2bf(src[7 * 64]);
        size_t obase = ((size_t)y * HDIM + d) * EMB + e0;
        *(ushort4*)(Vth + obase)     = h0;
        *(ushort4*)(Vth + obase + 4) = h1;
    } else {
        int i = ((f - 512) * 256 + threadIdx.x) * 8;
#pragma unroll
        for (int half = 0; half < 2; ++half) {
            float4 v = *(const float4*)(Wo + i + half * 4);
            ushort4 o;
            o.x = f2bf(v.x); o.y = f2bf(v.y); o.z = f2bf(v.z); o.w = f2bf(v.w);
            *(ushort4*)(Woh + i + half * 4) = o;
        }
    }
}

// ---------------------------------------------------------------------------
// Kernel 1a: Q/K projection, 3-pass split-bf16, LDS-FREE direct-global frags.
// A/B fragments are k-contiguous in global (16B/lane); L1 absorbs the 2x
// intra-block wave duplication.  No __syncthreads anywhere -> waves free-run.
// grid (32, 8, 2), block 256 = 2x2 waves, tile 128x128, BK=32.
// ---------------------------------------------------------------------------
__global__ __launch_bounds__(256, 2)
void qkv_z01(const u16* __restrict__ Xh, const u16* __restrict__ Xl,
             const u16* __restrict__ Wqh, const u16* __restrict__ Wql,
             const u16* __restrict__ Wkh, const u16* __restrict__ Wkl,
             u16* __restrict__ Qh, u16* __restrict__ Ql,
             u16* __restrict__ Kh, u16* __restrict__ Kl)
{
    const int z  = blockIdx.z;
    const int m0 = blockIdx.x * 128;
    const int n0 = blockIdx.y * 128;
    const int t    = threadIdx.x;
    const int wave = t >> 6, lane = t & 63;
    const int wm = wave & 1, wn = wave >> 1;
    const int l16 = lane & 15, quad = lane >> 4;

    const u16* Bh_g = z ? Wkh : Wqh;
    const u16* Bl_g = z ? Wkl : Wql;

    // per-wave fragment row bases (k-contiguous in global)
    const u16* Arow[4];  const u16* Brow[4];
#pragma unroll
    for (int i = 0; i < 4; ++i) {
        Arow[i] = Xh   + (size_t)(m0 + wm * 64 + 16 * i + l16) * EMB + quad * 8;
        Brow[i] = Bh_g + (size_t)(n0 + wn * 64 + 16 * i + l16) * EMB + quad * 8;
    }
    const ptrdiff_t dlo_a = Xl - Xh;       // same offsets in the lo arrays
    const ptrdiff_t dlo_b = Bl_g - Bh_g;

    f32x4 acc[4][4];
#pragma unroll
    for (int i = 0; i < 4; ++i)
#pragma unroll
        for (int j = 0; j < 4; ++j) acc[i][j] = (f32x4){0.f, 0.f, 0.f, 0.f};

    bf16x8 Ah[4], Al[4], Bh[4], Bl[4], nAh[4], nAl[4], nBh[4], nBl[4];
#define QK_LOAD(ah, al, bhh, bll, kk)                                          \
    do {                                                                       \
        _Pragma("unroll") for (int i = 0; i < 4; ++i) {                        \
            ah[i]  = *(const bf16x8*)(Arow[i] + (kk));                         \
            al[i]  = *(const bf16x8*)(Arow[i] + dlo_a + (kk));                 \
            bhh[i] = *(const bf16x8*)(Brow[i] + (kk));                         \
            bll[i] = *(const bf16x8*)(Brow[i] + dlo_b + (kk));                 \
        }                                                                      \
    } while (0)

    QK_LOAD(Ah, Al, Bh, Bl, 0);

    for (int k0 = 0; k0 < EMB; k0 += 32) {
        const int kn = (k0 + 32 < EMB) ? k0 + 32 : 0;
        QK_LOAD(nAh, nAl, nBh, nBl, kn);
#pragma unroll
        for (int i = 0; i < 4; ++i)
#pragma unroll
            for (int j = 0; j < 4; ++j) {
                acc[i][j] = __builtin_amdgcn_mfma_f32_16x16x32_bf16(Ah[i], Bh[j], acc[i][j], 0, 0, 0);
                acc[i][j] = __builtin_amdgcn_mfma_f32_16x16x32_bf16(Ah[i], Bl[j], acc[i][j], 0, 0, 0);
                acc[i][j] = __builtin_amdgcn_mfma_f32_16x16x32_bf16(Al[i], Bh[j], acc[i][j], 0, 0, 0);
            }
#pragma unroll
        for (int q = 0; q < 4; ++q) {
            Ah[q] = nAh[q]; Al[q] = nAl[q]; Bh[q] = nBh[q]; Bl[q] = nBl[q];
        }
    }
#undef QK_LOAD

    const int b = m0 >> 11;
    const int h = (n0 + wn * 64) >> 6;
    u16* Oh = z ? Kh : Qh;
    u16* Ol = z ? Kl : Ql;
    const float esc = z ? 1.0f : QSCALE;    // Q carries the softmax scale
#pragma unroll
    for (int i = 0; i < 4; ++i)
#pragma unroll
        for (int r = 0; r < 4; ++r) {
            int tt = (m0 & (SEQ - 1)) + wm * 64 + 16 * i + quad * 4 + r;
            size_t rowbase = ((size_t)(b * HEADS + h) * SEQ + tt) * HDIM;
#pragma unroll
            for (int j = 0; j < 4; ++j) {
                int d = 16 * j + l16;
                float v = acc[i][j][r] * esc;
                u16 hv = f2bf(v);
                Oh[rowbase + d] = hv;
                Ol[rowbase + d] = f2bf(v - bf2f(hv));
            }
        }
}

// ---------------------------------------------------------------------------
// Kernel 1b: V projection, 1-pass bf16, LDS-free.  Writes Vt[bh][d][t].
// ---------------------------------------------------------------------------
__global__ __launch_bounds__(256, 2)
void qkv_v(const u16* __restrict__ Xh, const u16* __restrict__ Wvt,
           u16* __restrict__ Vt)
{
    const int m0 = blockIdx.x * 128;
    const int n0 = blockIdx.y * 128;
    const int t    = threadIdx.x;
    const int wave = t >> 6, lane = t & 63;
    const int wm = wave & 1, wn = wave >> 1;
    const int l16 = lane & 15, quad = lane >> 4;

    const u16* Arow[4];  const u16* Brow[4];
#pragma unroll
    for (int i = 0; i < 4; ++i) {
        Arow[i] = Xh  + (size_t)(m0 + wm * 64 + 16 * i + l16) * EMB + quad * 8;
        Brow[i] = Wvt + (size_t)(n0 + wn * 64 + 16 * i + l16) * EMB + quad * 8;
    }

    f32x4 acc[4][4];
#pragma unroll
    for (int i = 0; i < 4; ++i)
#pragma unroll
        for (int j = 0; j < 4; ++j) acc[i][j] = (f32x4){0.f, 0.f, 0.f, 0.f};

    bf16x8 A[4], B[4], nA[4], nB[4];
#pragma unroll
    for (int i = 0; i < 4; ++i) {
        A[i] = *(const bf16x8*)(Arow[i]);
        B[i] = *(const bf16x8*)(Brow[i]);
    }

    for (int k0 = 0; k0 < EMB; k0 += 32) {
        const int kn = (k0 + 32 < EMB) ? k0 + 32 : 0;
#pragma unroll
        for (int i = 0; i < 4; ++i) {
            nA[i] = *(const bf16x8*)(Arow[i] + kn);
            nB[i] = *(const bf16x8*)(Brow[i] + kn);
        }
#pragma unroll
        for (int i = 0; i < 4; ++i)
#pragma unroll
            for (int j = 0; j < 4; ++j)
                acc[i][j] = __builtin_amdgcn_mfma_f32_16x16x32_bf16(A[i], B[j], acc[i][j], 0, 0, 0);
#pragma unroll
        for (int q = 0; q < 4; ++q) { A[q] = nA[q]; B[q] = nB[q]; }
    }

    const int b = m0 >> 11;
    const int h = (n0 + wn * 64) >> 6;
#pragma unroll
    for (int i = 0; i < 4; ++i)
#pragma unroll
        for (int j = 0; j < 4; ++j) {
            int d  = 16 * j + l16;
            int tt = (m0 & (SEQ - 1)) + wm * 64 + 16 * i + quad * 4;
            ushort4 o;
            o.x = f2bf(acc[i][j][0]); o.y = f2bf(acc[i][j][1]);
            o.z = f2bf(acc[i][j][2]); o.w = f2bf(acc[i][j][3]);
            *(ushort4*)(Vt + ((size_t)(b * HEADS + h) * HDIM + d) * SEQ + tt) = o;
        }
}

// ---------------------------------------------------------------------------
// Kernel 2: flash attention, transposed-score MFMA, 128-q block.
// K and V fragments now load DIRECT global->register (A-operand rows are
// k-contiguous in Kh/Kl and Vt); only P round-trips a 16KB LDS buffer,
// same-wave RAW -> ZERO __syncthreads in the kernel.
// grid (SEQ/128, BATCH*HEADS) = (16, 32).
// ---------------------------------------------------------------------------
__global__ __launch_bounds__(256, 2)
void attn_mfma(const u16* __restrict__ Qh, const u16* __restrict__ Ql,
               const u16* __restrict__ Kh, const u16* __restrict__ Kl,
               const u16* __restrict__ Vt, u16* __restrict__ Cb)
{
    const int qt0  = blockIdx.x * 128;
    const int bh   = blockIdx.y;
    const int t    = threadIdx.x;
    const int wave = t >> 6;
    const int lane = t & 63;
    const int l16  = lane & 15;
    const int quad = lane >> 4;

    __shared__ u16 Ps[8192];   // P [q:128][s:64], swizzled; same-wave use only

    const size_t bh_off = (size_t)bh * SEQ * HDIM;
    const u16* Qhb = Qh + bh_off;
    const u16* Qlb = Ql + bh_off;
    const u16* Khb = Kh + bh_off;
    const u16* Klb = Kl + bh_off;
    const u16* Vtb = Vt + bh_off;   // [64][SEQ]

    // Q fragments, 2 groups of 16 q-rows each
    bf16x8 aQh[2][2], aQl[2][2];
#pragma unroll
    for (int g = 0; g < 2; ++g) {
        const int qrow = qt0 + g * 64 + wave * 16 + l16;
        const u16* bH = Qhb + (size_t)qrow * HDIM + quad * 8;
        const u16* bL = Qlb + (size_t)qrow * HDIM + quad * 8;
        aQh[g][0] = *(const bf16x8*)(bH);
        aQh[g][1] = *(const bf16x8*)(bH + 32);
        aQl[g][0] = *(const bf16x8*)(bL);
        aQl[g][1] = *(const bf16x8*)(bL + 32);
    }

    // per-wave fragment row bases
    const u16* Krow[4];  const u16* Vrow[4];
#pragma unroll
    for (int i = 0; i < 4; ++i) {
        Krow[i] = Khb + (size_t)(16 * i + l16) * HDIM + quad * 8;   // + s*HDIM
        Vrow[i] = Vtb + (size_t)(16 * i + l16) * SEQ  + quad * 8;   // + s
    }
    const ptrdiff_t dlo_k = Klb - Khb;

    f32x4 accO[2][4];
    float m_i[2] = {-1e30f, -1e30f}, l_i[2] = {0.f, 0.f};
#pragma unroll
    for (int g = 0; g < 2; ++g)
#pragma unroll
        for (int j = 0; j < 4; ++j) accO[g][j] = (f32x4){0.f, 0.f, 0.f, 0.f};

    for (int s0 = 0; s0 < SEQ; s0 += 64) {
        // ---- direct-global K/V fragment loads (no LDS, no barriers) ----
        bf16x8 kh[2][4], kl[2][4], vv[2][4];
#pragma unroll
        for (int c = 0; c < 2; ++c)
#pragma unroll
            for (int i = 0; i < 4; ++i) {
                kh[c][i] = *(const bf16x8*)(Krow[i] + (size_t)s0 * HDIM + 32 * c);
                kl[c][i] = *(const bf16x8*)(Krow[i] + dlo_k + (size_t)s0 * HDIM + 32 * c);
                vv[c][i] = *(const bf16x8*)(Vrow[i] + s0 + 32 * c);
            }

        // ---- S^T = K Q^T (3-pass split), both q-groups share K frags ----
        f32x4 accS[2][4];
#pragma unroll
        for (int g = 0; g < 2; ++g)
#pragma unroll
            for (int i = 0; i < 4; ++i) accS[g][i] = (f32x4){0.f, 0.f, 0.f, 0.f};
#pragma unroll
        for (int c = 0; c < 2; ++c) {
#pragma unroll
            for (int i = 0; i < 4; ++i) {
                accS[0][i] = __builtin_amdgcn_mfma_f32_16x16x32_bf16(kh[c][i], aQh[0][c], accS[0][i], 0, 0, 0);
                accS[0][i] = __builtin_amdgcn_mfma_f32_16x16x32_bf16(kl[c][i], aQh[0][c], accS[0][i], 0, 0, 0);
                accS[0][i] = __builtin_amdgcn_mfma_f32_16x16x32_bf16(kh[c][i], aQl[0][c], accS[0][i], 0, 0, 0);
                accS[1][i] = __builtin_amdgcn_mfma_f32_16x16x32_bf16(kh[c][i], aQh[1][c], accS[1][i], 0, 0, 0);
                accS[1][i] = __builtin_amdgcn_mfma_f32_16x16x32_bf16(kl[c][i], aQh[1][c], accS[1][i], 0, 0, 0);
                accS[1][i] = __builtin_amdgcn_mfma_f32_16x16x32_bf16(kh[c][i], aQl[1][c], accS[1][i], 0, 0, 0);
            }
        }

        // ---- online softmax per group (lane owns q-row; 2 shfl each) ----
#pragma unroll
        for (int g = 0; g < 2; ++g) {
            float vmax = fmaxf(fmaxf(accS[g][0][0], accS[g][0][1]),
                               fmaxf(accS[g][0][2], accS[g][0][3]));
#pragma unroll
            for (int i = 1; i < 4; ++i)
                vmax = fmaxf(vmax, fmaxf(fmaxf(accS[g][i][0], accS[g][i][1]),
                                         fmaxf(accS[g][i][2], accS[g][i][3])));
            vmax = fmaxf(vmax, __shfl_xor(vmax, 16, 64));
            vmax = fmaxf(vmax, __shfl_xor(vmax, 32, 64));
            float mn   = fmaxf(m_i[g], vmax);
            float alph = fast_exp2(m_i[g] - mn);
            m_i[g] = mn;
            float P[4][4], s = 0.f;
#pragma unroll
            for (int i = 0; i < 4; ++i)
#pragma unroll
                for (int r = 0; r < 4; ++r) {
                    P[i][r] = fast_exp2(accS[g][i][r] - mn);
                    s += P[i][r];
                }
            s += __shfl_xor(s, 16, 64);
            s += __shfl_xor(s, 32, 64);
            l_i[g] = l_i[g] * alph + s;
#pragma unroll
            for (int j = 0; j < 4; ++j) accO[g][j] *= alph;

            const int prow = g * 64 + wave * 16 + l16;
#pragma unroll
            for (int i = 0; i < 4; ++i) {
                uint2 pv;
                pv.x = pk_trunc(P[i][0], P[i][1]);
                pv.y = pk_trunc(P[i][2], P[i][3]);
                *(uint2*)&Ps[SWZ(prow, 2 * i + (quad >> 1)) + ((quad & 1) << 2)] = pv;
            }
        }

        // ---- O^T += V^T P^T  (V frags direct-global, P from own LDS rows) ----
#pragma unroll
        for (int c = 0; c < 2; ++c) {
            bf16x8 bP0 = *(const bf16x8*)&Ps[SWZ(wave * 16 + l16,      4 * c + quad)];
            bf16x8 bP1 = *(const bf16x8*)&Ps[SWZ(64 + wave * 16 + l16, 4 * c + quad)];
#pragma unroll
            for (int j = 0; j < 4; ++j) {
                accO[0][j] = __builtin_amdgcn_mfma_f32_16x16x32_bf16(vv[c][j], bP0, accO[0][j], 0, 0, 0);
                accO[1][j] = __builtin_amdgcn_mfma_f32_16x16x32_bf16(vv[c][j], bP1, accO[1][j], 0, 0, 0);
            }
        }
    }

    const int b = bh >> 4, h = bh & 15;
#pragma unroll
    for (int g = 0; g < 2; ++g) {
        const int row = qt0 + g * 64 + wave * 16 + l16;
        const float inv = 1.f / l_i[g];
#pragma unroll
        for (int j = 0; j < 4; ++j) {
            ushort4 o;
            o.x = f2bf(accO[g][j][0] * inv); o.y = f2bf(accO[g][j][1] * inv);
            o.z = f2bf(accO[g][j][2] * inv); o.w = f2bf(accO[g][j][3] * inv);
            *(ushort4*)&Cb[((size_t)b * SEQ + row) * EMB + h * HDIM + 16 * j + quad * 4] = o;
        }
    }
}

// ---------------------------------------------------------------------------
// Kernel 3: Y = X + C @ Wo^T, bf16 MFMA, 128x128, LDS-free.  grid (32, 8).
// ---------------------------------------------------------------------------
__global__ __launch_bounds__(256, 2)
void oproj_mfma(const u16* __restrict__ Cb, const u16* __restrict__ Woh,
                const float* __restrict__ X, float* __restrict__ Y)
{
    const int m0 = blockIdx.x * 128;
    const int n0 = blockIdx.y * 128;
    const int t    = threadIdx.x;
    const int wave = t >> 6, lane = t & 63;
    const int wm = wave & 1, wn = wave >> 1;
    const int l16 = lane & 15, quad = lane >> 4;

    const u16* Arow[4];  const u16* Brow[4];
#pragma unroll
    for (int i = 0; i < 4; ++i) {
        Arow[i] = Cb  + (size_t)(m0 + wm * 64 + 16 * i + l16) * EMB + quad * 8;
        Brow[i] = Woh + (size_t)(n0 + wn * 64 + 16 * i + l16) * EMB + quad * 8;
    }

    f32x4 acc[4][4];
#pragma unroll
    for (int i = 0; i < 4; ++i)
#pragma unroll
        for (int j = 0; j < 4; ++j) acc[i][j] = (f32x4){0.f, 0.f, 0.f, 0.f};

    bf16x8 A[4], B[4], nA[4], nB[4];
#pragma unroll
    for (int i = 0; i < 4; ++i) {
        A[i] = *(const bf16x8*)(Arow[i]);
        B[i] = *(const bf16x8*)(Brow[i]);
    }

    for (int k0 = 0; k0 < EMB; k0 += 32) {
        const int kn = (k0 + 32 < EMB) ? k0 + 32 : 0;
#pragma unroll
        for (int i = 0; i < 4; ++i) {
            nA[i] = *(const bf16x8*)(Arow[i] + kn);
            nB[i] = *(const bf16x8*)(Brow[i] + kn);
        }
#pragma unroll
        for (int i = 0; i < 4; ++i)
#pragma unroll
            for (int j = 0; j < 4; ++j)
                acc[i][j] = __builtin_amdgcn_mfma_f32_16x16x32_bf16(A[i], B[j], acc[i][j], 0, 0, 0);
#pragma unroll
        for (int q = 0; q < 4; ++q) { A[q] = nA[q]; B[q] = nB[q]; }
    }

#pragma unroll
    for (int i = 0; i < 4; ++i)
#pragma unroll
        for (int r = 0; r < 4; ++r) {
            int m = m0 + wm * 64 + 16 * i + quad * 4 + r;
#pragma unroll
            for (int j = 0; j < 4; ++j) {
                int n = n0 + wn * 64 + 16 * j + l16;
                Y[(size_t)m * EMB + n] = acc[i][j][r] + X[(size_t)m * EMB + n];
            }
        }
}

// ---------------------------------------------------------------------------
// Workspace map (u16 units, 32M total = 64 MiB):
//   [0]   Qh 4M   [4M] Ql   [8M] Kh   [12M] Kl   [16M] Vt
//   [20M] Xh 4M   (-> Cb after qkv_v)
//   [24M] Xl 4M   (-> Woh after qkv_z01, written by prep2)
//   [28M] Wtq_h 1M (-> Wvt after qkv_z01, written by prep2), Wtq_l, Wtk_h, Wtk_l
// ---------------------------------------------------------------------------
extern "C" void kernel_launch(void* const* d_in, const int* in_sizes, int n_in,
                              void* d_out, int out_size, void* d_ws,
                              size_t ws_size, hipStream_t stream)
{
    const float* x  = (const float*)d_in[0];
    const float* Wq = (const float*)d_in[1];
    const float* Wk = (const float*)d_in[2];
    const float* Wv = (const float*)d_in[3];
    const float* Wo = (const float*)d_in[4];
    float* Y = (float*)d_out;

    const size_t NPER = (size_t)MROWS * EMB;   // 4,194,304
    u16* base  = (u16*)d_ws;
    u16* Qh    = base;
    u16* Ql    = Qh + NPER;
    u16* Kh    = Ql + NPER;
    u16* Kl    = Kh + NPER;
    u16* Vt    = Kl + NPER;
    u16* Xh    = Vt + NPER;
    u16* Xl    = Xh + NPER;
    u16* Wtq_h = Xl + NPER;
    u16* Wtq_l = Wtq_h + EMB * EMB;
    u16* Wtk_h = Wtq_l + EMB * EMB;
    u16* Wtk_l = Wtk_h + EMB * EMB;
    u16* Wvt   = Wtq_h;   // alias: Wtq dead after qkv_z01
    u16* Cb    = Xh;      // alias: Xh dead after qkv_v
    u16* Woh   = Xl;      // alias: Xl dead after qkv_z01

    prep1<<<dim3(3072), 256, 0, stream>>>(x, Wq, Wk, Xh, Xl,
                                          Wtq_h, Wtq_l, Wtk_h, Wtk_l);
    qkv_z01<<<dim3(32, 8, 2), 256, 0, stream>>>(Xh, Xl, Wtq_h, Wtq_l,
                                                Wtk_h, Wtk_l, Qh, Ql, Kh, Kl);
    prep2<<<dim3(1024), 256, 0, stream>>>(Wv, Wo, Wvt, Woh);
    qkv_v<<<dim3(32, 8), 256, 0, stream>>>(Xh, Wvt, Vt);
    attn_mfma<<<dim3(SEQ / 128, BATCH * HEADS), 256, 0, stream>>>(Qh, Ql, Kh, Kl,
                                                                  Vt, Cb);
    oproj_mfma<<<dim3(32, 8), 256, 0, stream>>>(Cb, Woh, x, Y);
}

// Round 9
// 269.089 us; speedup vs baseline: 1.7418x; 1.7418x over previous
//
#include <hip/hip_runtime.h>

#define EMB   1024
#define HEADS 16
#define HDIM  64
#define BATCH 2
#define SEQ   2048
#define MROWS (BATCH*SEQ)   // 4096
#define STR   40            // qkv/oproj LDS k-stride in u16: 80 B
#define QSCALE 0.1803368801111204f   // 0.125 * log2(e): Q pre-scale -> exp2 softmax

typedef __attribute__((ext_vector_type(8))) short bf16x8;   // 8 bf16 (4 VGPRs)
typedef __attribute__((ext_vector_type(4))) float f32x4;    // MFMA C/D
typedef unsigned short u16;

__device__ __forceinline__ u16 f2bf(float f) {              // round-to-nearest-even
    unsigned u = __float_as_uint(f);
    u += 0x7fffu + ((u >> 16) & 1u);
    return (u16)(u >> 16);
}
__device__ __forceinline__ float bf2f(u16 h) {
    return __uint_as_float((unsigned)h << 16);
}
__device__ __forceinline__ float fast_exp2(float x) {
#if __has_builtin(__builtin_amdgcn_exp2f)
    return __builtin_amdgcn_exp2f(x);
#else
    return __expf(x * 0.6931471805599453f);
#endif
}
// pack two floats -> two truncated bf16 in one v_perm_b32 (lo in [15:0])
__device__ __forceinline__ unsigned pk_trunc(float lo, float hi) {
    return __builtin_amdgcn_perm(__float_as_uint(hi), __float_as_uint(lo),
                                 0x07060302u);
}

// XOR-swizzled LDS offset (u16 units): 64-u16 rows, 8-u16 chunks, chunk^=row&7.
#define SWZ(r, ch) ((((r) << 6)) + ((((ch) ^ ((r) & 7))) << 3))

// ---------------------------------------------------------------------------
// prep1: fused  [bx<2048] X->Xh/Xl split  |  [else] Wq/Wk transpose+hi/lo.
// ---------------------------------------------------------------------------
__global__ __launch_bounds__(256)
void prep1(const float* __restrict__ X, const float* __restrict__ Wq,
           const float* __restrict__ Wk,
           u16* __restrict__ Xh, u16* __restrict__ Xl,
           u16* __restrict__ Qth, u16* __restrict__ Qtl,
           u16* __restrict__ Kth, u16* __restrict__ Ktl)
{
    const int bx = blockIdx.x;
    if (bx < 2048) {                       // xsplit: 8 elems/thread
        int i = (bx * 256 + threadIdx.x) * 8;
#pragma unroll
        for (int half = 0; half < 2; ++half) {
            float4 v = *(const float4*)(X + i + half * 4);
            ushort4 hi, lo;
            hi.x = f2bf(v.x); lo.x = f2bf(v.x - bf2f(hi.x));
            hi.y = f2bf(v.y); lo.y = f2bf(v.y - bf2f(hi.y));
            hi.z = f2bf(v.z); lo.z = f2bf(v.z - bf2f(hi.z));
            hi.w = f2bf(v.w); lo.w = f2bf(v.w - bf2f(hi.w));
            *(ushort4*)(Xh + i + half * 4) = hi;
            *(ushort4*)(Xl + i + half * 4) = lo;
        }
    } else {                               // wtrans: [16][1024][64] -> [h*64+d][e]
        const int f = bx - 2048;           // 0..1023
        const int z = f >> 9, y = (f >> 5) & 15, x = f & 31;
        const float* W  = z ? Wk  : Wq;
        u16* Oh         = z ? Kth : Qth;
        u16* Ol         = z ? Ktl : Qtl;
        const int d  = threadIdx.x & 63;
        const int e0 = (x * 4 + (threadIdx.x >> 6)) * 8;
        const float* src = W + ((size_t)y * EMB + e0) * HDIM + d;
        ushort4 h0, h1, l0, l1;
        float v; u16 hv;
        v = src[0 * 64]; hv = f2bf(v); h0.x = hv; l0.x = f2bf(v - bf2f(hv));
        v = src[1 * 64]; hv = f2bf(v); h0.y = hv; l0.y = f2bf(v - bf2f(hv));
        v = src[2 * 64]; hv = f2bf(v); h0.z = hv; l0.z = f2bf(v - bf2f(hv));
        v = src[3 * 64]; hv = f2bf(v); h0.w = hv; l0.w = f2bf(v - bf2f(hv));
        v = src[4 * 64]; hv = f2bf(v); h1.x = hv; l1.x = f2bf(v - bf2f(hv));
        v = src[5 * 64]; hv = f2bf(v); h1.y = hv; l1.y = f2bf(v - bf2f(hv));
        v = src[6 * 64]; hv = f2bf(v); h1.z = hv; l1.z = f2bf(v - bf2f(hv));
        v = src[7 * 64]; hv = f2bf(v); h1.w = hv; l1.w = f2bf(v - bf2f(hv));
        size_t obase = ((size_t)y * HDIM + d) * EMB + e0;
        *(ushort4*)(Oh + obase)     = h0;
        *(ushort4*)(Oh + obase + 4) = h1;
        *(ushort4*)(Ol + obase)     = l0;
        *(ushort4*)(Ol + obase + 4) = l1;
    }
}

// ---------------------------------------------------------------------------
// prep2 (after qkv_z01): [f<512] Wv transpose->bf16  |  [else] Wo -> bf16.
// ---------------------------------------------------------------------------
__global__ __launch_bounds__(256)
void prep2(const float* __restrict__ Wv, const float* __restrict__ Wo,
           u16* __restrict__ Vth, u16* __restrict__ Woh)
{
    const int f = blockIdx.x;
    if (f < 512) {
        const int y = f >> 5, x = f & 31;
        const int d  = threadIdx.x & 63;
        const int e0 = (x * 4 + (threadIdx.x >> 6)) * 8;
        const float* src = Wv + ((size_t)y * EMB + e0) * HDIM + d;
        ushort4 h0, h1;
        h0.x = f2bf(src[0 * 64]); h0.y = f2bf(src[1 * 64]);
        h0.z = f2bf(src[2 * 64]); h0.w = f2bf(src[3 * 64]);
        h1.x = f2bf(src[4 * 64]); h1.y = f2bf(src[5 * 64]);
        h1.z = f2bf(src[6 * 64]); h1.w = f2bf(src[7 * 64]);
        size_t obase = ((size_t)y * HDIM + d) * EMB + e0;
        *(ushort4*)(Vth + obase)     = h0;
        *(ushort4*)(Vth + obase + 4) = h1;
    } else {
        int i = ((f - 512) * 256 + threadIdx.x) * 8;
#pragma unroll
        for (int half = 0; half < 2; ++half) {
            float4 v = *(const float4*)(Wo + i + half * 4);
            ushort4 o;
            o.x = f2bf(v.x); o.y = f2bf(v.y); o.z = f2bf(v.z); o.w = f2bf(v.w);
            *(ushort4*)(Woh + i + half * 4) = o;
        }
    }
}

// ---------------------------------------------------------------------------
// Kernel 1a: Q/K projection, 3-pass split-bf16, 2-deep register pipeline
// (R7-proven).  LDS staging = the coalescing transform; dbuf would need
// 80KB > 64KB static limit, so keep 2-barrier form here.
// ---------------------------------------------------------------------------
__global__ __launch_bounds__(256, 2)
void qkv_z01(const u16* __restrict__ Xh, const u16* __restrict__ Xl,
             const u16* __restrict__ Wqh, const u16* __restrict__ Wql,
             const u16* __restrict__ Wkh, const u16* __restrict__ Wkl,
             u16* __restrict__ Qh, u16* __restrict__ Ql,
             u16* __restrict__ Kh, u16* __restrict__ Kl)
{
    const int z  = blockIdx.z;
    const int m0 = blockIdx.x * 128;
    const int n0 = blockIdx.y * 128;
    const int t    = threadIdx.x;
    const int wave = t >> 6, lane = t & 63;
    const int wm = wave & 1, wn = wave >> 1;
    const int l16 = lane & 15, quad = lane >> 4;

    __shared__ u16 Ahs[128][STR];
    __shared__ u16 Als[128][STR];
    __shared__ u16 Bhs[128][STR];
    __shared__ u16 Bls[128][STR];

    const u16* Bh_g = z ? Wkh : Wqh;
    const u16* Bl_g = z ? Wkl : Wql;

    const int ar0 = t >> 2, ak = (t & 3) * 8, ar1 = ar0 + 64;

    f32x4 acc[4][4];
#pragma unroll
    for (int i = 0; i < 4; ++i)
#pragma unroll
        for (int j = 0; j < 4; ++j) acc[i][j] = (f32x4){0.f, 0.f, 0.f, 0.f};

    bf16x8 cur[8], nxt[8], nx2[8];
#define QK_LOAD(dst, kk)                                                        \
    do {                                                                        \
        dst[0] = *(const bf16x8*)(Xh  + (size_t)(m0 + ar0) * EMB + (kk) + ak);  \
        dst[1] = *(const bf16x8*)(Xh  + (size_t)(m0 + ar1) * EMB + (kk) + ak);  \
        dst[2] = *(const bf16x8*)(Xl  + (size_t)(m0 + ar0) * EMB + (kk) + ak);  \
        dst[3] = *(const bf16x8*)(Xl  + (size_t)(m0 + ar1) * EMB + (kk) + ak);  \
        dst[4] = *(const bf16x8*)(Bh_g + (size_t)(n0 + ar0) * EMB + (kk) + ak); \
        dst[5] = *(const bf16x8*)(Bh_g + (size_t)(n0 + ar1) * EMB + (kk) + ak); \
        dst[6] = *(const bf16x8*)(Bl_g + (size_t)(n0 + ar0) * EMB + (kk) + ak); \
        dst[7] = *(const bf16x8*)(Bl_g + (size_t)(n0 + ar1) * EMB + (kk) + ak); \
    } while (0)

    QK_LOAD(cur, 0);
    QK_LOAD(nxt, 32);

    for (int k0 = 0; k0 < EMB; k0 += 32) {
        __syncthreads();
        *(bf16x8*)&Ahs[ar0][ak] = cur[0];  *(bf16x8*)&Ahs[ar1][ak] = cur[1];
        *(bf16x8*)&Als[ar0][ak] = cur[2];  *(bf16x8*)&Als[ar1][ak] = cur[3];
        *(bf16x8*)&Bhs[ar0][ak] = cur[4];  *(bf16x8*)&Bhs[ar1][ak] = cur[5];
        *(bf16x8*)&Bls[ar0][ak] = cur[6];  *(bf16x8*)&Bls[ar1][ak] = cur[7];
        __syncthreads();

        const int kn = (k0 + 64 < EMB) ? k0 + 64 : 0;   // dummy reload at end
        QK_LOAD(nx2, kn);

        bf16x8 B4h[4], B4l[4];
#pragma unroll
        for (int j = 0; j < 4; ++j) {
            B4h[j] = *(const bf16x8*)&Bhs[wn * 64 + 16 * j + l16][quad * 8];
            B4l[j] = *(const bf16x8*)&Bls[wn * 64 + 16 * j + l16][quad * 8];
        }
#pragma unroll
        for (int i = 0; i < 4; ++i) {
            bf16x8 Ai_h = *(const bf16x8*)&Ahs[wm * 64 + 16 * i + l16][quad * 8];
            bf16x8 Ai_l = *(const bf16x8*)&Als[wm * 64 + 16 * i + l16][quad * 8];
#pragma unroll
            for (int j = 0; j < 4; ++j) {
                acc[i][j] = __builtin_amdgcn_mfma_f32_16x16x32_bf16(Ai_h, B4h[j], acc[i][j], 0, 0, 0);
                acc[i][j] = __builtin_amdgcn_mfma_f32_16x16x32_bf16(Ai_h, B4l[j], acc[i][j], 0, 0, 0);
                acc[i][j] = __builtin_amdgcn_mfma_f32_16x16x32_bf16(Ai_l, B4h[j], acc[i][j], 0, 0, 0);
            }
        }
#pragma unroll
        for (int q = 0; q < 8; ++q) { cur[q] = nxt[q]; nxt[q] = nx2[q]; }
    }
#undef QK_LOAD

    const int b = m0 >> 11;
    const int h = (n0 + wn * 64) >> 6;
    u16* Oh = z ? Kh : Qh;
    u16* Ol = z ? Kl : Ql;
    const float esc = z ? 1.0f : QSCALE;    // Q carries the softmax scale
#pragma unroll
    for (int i = 0; i < 4; ++i)
#pragma unroll
        for (int r = 0; r < 4; ++r) {
            int tt = (m0 & (SEQ - 1)) + wm * 64 + 16 * i + quad * 4 + r;
            size_t rowbase = ((size_t)(b * HEADS + h) * SEQ + tt) * HDIM;
#pragma unroll
            for (int j = 0; j < 4; ++j) {
                int d = 16 * j + l16;
                float v = acc[i][j][r] * esc;
                u16 hv = f2bf(v);
                Oh[rowbase + d] = hv;
                Ol[rowbase + d] = f2bf(v - bf2f(hv));
            }
        }
}

// ---------------------------------------------------------------------------
// Kernel 1b: V projection, 1-pass bf16, DOUBLE-BUFFERED LDS (1 barrier/tile;
// loads for k+1 in flight across the whole compute phase, vmcnt drained at
// the tail LDS-write).  Writes Vt[bh][d][t].
// ---------------------------------------------------------------------------
__global__ __launch_bounds__(256, 2)
void qkv_v(const u16* __restrict__ Xh, const u16* __restrict__ Wvt,
           u16* __restrict__ Vt)
{
    const int m0 = blockIdx.x * 128;
    const int n0 = blockIdx.y * 128;
    const int t    = threadIdx.x;
    const int wave = t >> 6, lane = t & 63;
    const int wm = wave & 1, wn = wave >> 1;
    const int l16 = lane & 15, quad = lane >> 4;

    __shared__ u16 Ahs[2][128][STR];
    __shared__ u16 Bhs[2][128][STR];

    const int ar0 = t >> 2, ak = (t & 3) * 8, ar1 = ar0 + 64;

    f32x4 acc[4][4];
#pragma unroll
    for (int i = 0; i < 4; ++i)
#pragma unroll
        for (int j = 0; j < 4; ++j) acc[i][j] = (f32x4){0.f, 0.f, 0.f, 0.f};

    bf16x8 cur[4];
#define V_LOAD(dst, kk)                                                         \
    do {                                                                        \
        dst[0] = *(const bf16x8*)(Xh  + (size_t)(m0 + ar0) * EMB + (kk) + ak);  \
        dst[1] = *(const bf16x8*)(Xh  + (size_t)(m0 + ar1) * EMB + (kk) + ak);  \
        dst[2] = *(const bf16x8*)(Wvt + (size_t)(n0 + ar0) * EMB + (kk) + ak);  \
        dst[3] = *(const bf16x8*)(Wvt + (size_t)(n0 + ar1) * EMB + (kk) + ak);  \
    } while (0)

    V_LOAD(cur, 0);
    *(bf16x8*)&Ahs[0][ar0][ak] = cur[0];  *(bf16x8*)&Ahs[0][ar1][ak] = cur[1];
    *(bf16x8*)&Bhs[0][ar0][ak] = cur[2];  *(bf16x8*)&Bhs[0][ar1][ak] = cur[3];

    for (int k0 = 0; k0 < EMB; k0 += 32) {
        const int buf = (k0 >> 5) & 1;
        __syncthreads();                        // buf fully written; buf^1 free
        const int kn = (k0 + 32 < EMB) ? k0 + 32 : 0;
        V_LOAD(cur, kn);                        // in flight during compute

        bf16x8 B4[4];
#pragma unroll
        for (int j = 0; j < 4; ++j)
            B4[j] = *(const bf16x8*)&Bhs[buf][wn * 64 + 16 * j + l16][quad * 8];
#pragma unroll
        for (int i = 0; i < 4; ++i) {
            bf16x8 Ai = *(const bf16x8*)&Ahs[buf][wm * 64 + 16 * i + l16][quad * 8];
#pragma unroll
            for (int j = 0; j < 4; ++j)
                acc[i][j] = __builtin_amdgcn_mfma_f32_16x16x32_bf16(Ai, B4[j], acc[i][j], 0, 0, 0);
        }
        // tail: stash k+1 into the other buffer (vmcnt drains here, post-MFMA)
        *(bf16x8*)&Ahs[buf ^ 1][ar0][ak] = cur[0];
        *(bf16x8*)&Ahs[buf ^ 1][ar1][ak] = cur[1];
        *(bf16x8*)&Bhs[buf ^ 1][ar0][ak] = cur[2];
        *(bf16x8*)&Bhs[buf ^ 1][ar1][ak] = cur[3];
    }
#undef V_LOAD

    const int b = m0 >> 11;
    const int h = (n0 + wn * 64) >> 6;
#pragma unroll
    for (int i = 0; i < 4; ++i)
#pragma unroll
        for (int j = 0; j < 4; ++j) {
            int d  = 16 * j + l16;
            int tt = (m0 & (SEQ - 1)) + wm * 64 + 16 * i + quad * 4;
            ushort4 o;
            o.x = f2bf(acc[i][j][0]); o.y = f2bf(acc[i][j][1]);
            o.z = f2bf(acc[i][j][2]); o.w = f2bf(acc[i][j][3]);
            *(ushort4*)(Vt + ((size_t)(b * HEADS + h) * HDIM + d) * SEQ + tt) = o;
        }
}

// ---------------------------------------------------------------------------
// Kernel 2: flash attention, transposed-score MFMA, 128-q block, DOUBLE-
// BUFFERED K/V LDS: ONE __syncthreads per s-tile; K/V loads for s+1 issue
// right after the barrier and drain at the tail LDS-write, after all MFMA/
// softmax of tile s.  XOR swizzle, log2 softmax, v_perm P-pack retained.
// LDS = 2*(8+8+8)KB + 16KB Ps = 64KB -> 2 blocks/CU.
// ---------------------------------------------------------------------------
__global__ __launch_bounds__(256, 2)
void attn_mfma(const u16* __restrict__ Qh, const u16* __restrict__ Ql,
               const u16* __restrict__ Kh, const u16* __restrict__ Kl,
               const u16* __restrict__ Vt, u16* __restrict__ Cb)
{
    const int qt0  = blockIdx.x * 128;
    const int bh   = blockIdx.y;
    const int t    = threadIdx.x;
    const int wave = t >> 6;
    const int lane = t & 63;
    const int l16  = lane & 15;
    const int quad = lane >> 4;

    __shared__ u16 Ksh[2][4096];   // K hi [s][d], swizzled
    __shared__ u16 Ksl[2][4096];   // K lo [s][d], swizzled
    __shared__ u16 Vs [2][4096];   // V^T  [d][s], swizzled
    __shared__ u16 Ps [8192];      // P [q:128][s:64]; same-wave rows only

    const size_t bh_off = (size_t)bh * SEQ * HDIM;
    const u16* Qhb = Qh + bh_off;
    const u16* Qlb = Ql + bh_off;
    const u16* Khb = Kh + bh_off;
    const u16* Klb = Kl + bh_off;
    const u16* Vtb = Vt + bh_off;   // [64][SEQ]

    // Q fragments, 2 groups of 16 q-rows each (g*64 apart)
    bf16x8 aQh[2][2], aQl[2][2];
#pragma unroll
    for (int g = 0; g < 2; ++g) {
        const int qrow = qt0 + g * 64 + wave * 16 + l16;
        const u16* bH = Qhb + (size_t)qrow * HDIM + quad * 8;
        const u16* bL = Qlb + (size_t)qrow * HDIM + quad * 8;
        aQh[g][0] = *(const bf16x8*)(bH);
        aQh[g][1] = *(const bf16x8*)(bH + 32);
        aQl[g][0] = *(const bf16x8*)(bL);
        aQl[g][1] = *(const bf16x8*)(bL + 32);
    }

    f32x4 accO[2][4];
    float m_i[2] = {-1e30f, -1e30f}, l_i[2] = {0.f, 0.f};
#pragma unroll
    for (int g = 0; g < 2; ++g)
#pragma unroll
        for (int j = 0; j < 4; ++j) accO[g][j] = (f32x4){0.f, 0.f, 0.f, 0.f};

    const int sr0 = t >> 3, sch = t & 7, sr1 = sr0 + 32;
    const int gc  = sch * 8;
    const int so0 = SWZ(sr0, sch), so1 = SWZ(sr1, sch);

    bf16x8 cur[6];
#define KV_LOAD(dst, ss)                                                       \
    do {                                                                       \
        dst[0] = *(const bf16x8*)(Khb + (size_t)((ss) + sr0) * HDIM + gc);     \
        dst[1] = *(const bf16x8*)(Khb + (size_t)((ss) + sr1) * HDIM + gc);     \
        dst[2] = *(const bf16x8*)(Klb + (size_t)((ss) + sr0) * HDIM + gc);     \
        dst[3] = *(const bf16x8*)(Klb + (size_t)((ss) + sr1) * HDIM + gc);     \
        dst[4] = *(const bf16x8*)(Vtb + (size_t)sr0 * SEQ + (ss) + gc);        \
        dst[5] = *(const bf16x8*)(Vtb + (size_t)sr1 * SEQ + (ss) + gc);        \
    } while (0)

    KV_LOAD(cur, 0);
    *(bf16x8*)&Ksh[0][so0] = cur[0];  *(bf16x8*)&Ksh[0][so1] = cur[1];
    *(bf16x8*)&Ksl[0][so0] = cur[2];  *(bf16x8*)&Ksl[0][so1] = cur[3];
    *(bf16x8*)&Vs [0][so0] = cur[4];  *(bf16x8*)&Vs [0][so1] = cur[5];

    for (int s0 = 0; s0 < SEQ; s0 += 64) {
        const int buf = (s0 >> 6) & 1;
        __syncthreads();                   // buf written by all; buf^1 reads done
        const int sn = (s0 + 64 < SEQ) ? s0 + 64 : 0;
        KV_LOAD(cur, sn);                  // in flight across entire compute

        // ---- S^T = K Q^T (3-pass split), both q-groups share K reads ----
        f32x4 accS[2][4];
#pragma unroll
        for (int g = 0; g < 2; ++g)
#pragma unroll
            for (int i = 0; i < 4; ++i) accS[g][i] = (f32x4){0.f, 0.f, 0.f, 0.f};
#pragma unroll
        for (int c = 0; c < 2; ++c) {
#pragma unroll
            for (int i = 0; i < 4; ++i) {
                bf16x8 kh_ = *(const bf16x8*)&Ksh[buf][SWZ(16 * i + l16, 4 * c + quad)];
                bf16x8 kl_ = *(const bf16x8*)&Ksl[buf][SWZ(16 * i + l16, 4 * c + quad)];
                accS[0][i] = __builtin_amdgcn_mfma_f32_16x16x32_bf16(kh_, aQh[0][c], accS[0][i], 0, 0, 0);
                accS[0][i] = __builtin_amdgcn_mfma_f32_16x16x32_bf16(kl_, aQh[0][c], accS[0][i], 0, 0, 0);
                accS[0][i] = __builtin_amdgcn_mfma_f32_16x16x32_bf16(kh_, aQl[0][c], accS[0][i], 0, 0, 0);
                accS[1][i] = __builtin_amdgcn_mfma_f32_16x16x32_bf16(kh_, aQh[1][c], accS[1][i], 0, 0, 0);
                accS[1][i] = __builtin_amdgcn_mfma_f32_16x16x32_bf16(kl_, aQh[1][c], accS[1][i], 0, 0, 0);
                accS[1][i] = __builtin_amdgcn_mfma_f32_16x16x32_bf16(kh_, aQl[1][c], accS[1][i], 0, 0, 0);
            }
        }

        // ---- online softmax per group (lane owns q-row; 2 shfl each) ----
#pragma unroll
        for (int g = 0; g < 2; ++g) {
            float vmax = fmaxf(fmaxf(accS[g][0][0], accS[g][0][1]),
                               fmaxf(accS[g][0][2], accS[g][0][3]));
#pragma unroll
            for (int i = 1; i < 4; ++i)
                vmax = fmaxf(vmax, fmaxf(fmaxf(accS[g][i][0], accS[g][i][1]),
                                         fmaxf(accS[g][i][2], accS[g][i][3])));
            vmax = fmaxf(vmax, __shfl_xor(vmax, 16, 64));
            vmax = fmaxf(vmax, __shfl_xor(vmax, 32, 64));
            float mn   = fmaxf(m_i[g], vmax);
            float alph = fast_exp2(m_i[g] - mn);
            m_i[g] = mn;
            float P[4][4], s = 0.f;
#pragma unroll
            for (int i = 0; i < 4; ++i)
#pragma unroll
                for (int r = 0; r < 4; ++r) {
                    P[i][r] = fast_exp2(accS[g][i][r] - mn);
                    s += P[i][r];
                }
            s += __shfl_xor(s, 16, 64);
            s += __shfl_xor(s, 32, 64);
            l_i[g] = l_i[g] * alph + s;
#pragma unroll
            for (int j = 0; j < 4; ++j) accO[g][j] *= alph;

            const int prow = g * 64 + wave * 16 + l16;
#pragma unroll
            for (int i = 0; i < 4; ++i) {
                uint2 pv;
                pv.x = pk_trunc(P[i][0], P[i][1]);
                pv.y = pk_trunc(P[i][2], P[i][3]);
                *(uint2*)&Ps[SWZ(prow, 2 * i + (quad >> 1)) + ((quad & 1) << 2)] = pv;
            }
        }

        // ---- O^T += V^T P^T  (V reads shared across both q-groups) ----
#pragma unroll
        for (int c = 0; c < 2; ++c) {
            bf16x8 bP0 = *(const bf16x8*)&Ps[SWZ(wave * 16 + l16,      4 * c + quad)];
            bf16x8 bP1 = *(const bf16x8*)&Ps[SWZ(64 + wave * 16 + l16, 4 * c + quad)];
#pragma unroll
            for (int j = 0; j < 4; ++j) {
                bf16x8 aV = *(const bf16x8*)&Vs[buf][SWZ(16 * j + l16, 4 * c + quad)];
                accO[0][j] = __builtin_amdgcn_mfma_f32_16x16x32_bf16(aV, bP0, accO[0][j], 0, 0, 0);
                accO[1][j] = __builtin_amdgcn_mfma_f32_16x16x32_bf16(aV, bP1, accO[1][j], 0, 0, 0);
            }
        }

        // tail: stash tile s+1 into buf^1 (vmcnt drains here, post-compute)
        *(bf16x8*)&Ksh[buf ^ 1][so0] = cur[0];  *(bf16x8*)&Ksh[buf ^ 1][so1] = cur[1];
        *(bf16x8*)&Ksl[buf ^ 1][so0] = cur[2];  *(bf16x8*)&Ksl[buf ^ 1][so1] = cur[3];
        *(bf16x8*)&Vs [buf ^ 1][so0] = cur[4];  *(bf16x8*)&Vs [buf ^ 1][so1] = cur[5];
    }
#undef KV_LOAD

    const int b = bh >> 4, h = bh & 15;
#pragma unroll
    for (int g = 0; g < 2; ++g) {
        const int row = qt0 + g * 64 + wave * 16 + l16;
        const float inv = 1.f / l_i[g];
#pragma unroll
        for (int j = 0; j < 4; ++j) {
            ushort4 o;
            o.x = f2bf(accO[g][j][0] * inv); o.y = f2bf(accO[g][j][1] * inv);
            o.z = f2bf(accO[g][j][2] * inv); o.w = f2bf(accO[g][j][3] * inv);
            *(ushort4*)&Cb[((size_t)b * SEQ + row) * EMB + h * HDIM + 16 * j + quad * 4] = o;
        }
    }
}

// ---------------------------------------------------------------------------
// Kernel 3: Y = X + C @ Wo^T, bf16 MFMA, 128x128, double-buffered LDS.
// ---------------------------------------------------------------------------
__global__ __launch_bounds__(256, 2)
void oproj_mfma(const u16* __restrict__ Cb, const u16* __restrict__ Woh,
                const float* __restrict__ X, float* __restrict__ Y)
{
    const int m0 = blockIdx.x * 128;
    const int n0 = blockIdx.y * 128;
    const int t    = threadIdx.x;
    const int wave = t >> 6, lane = t & 63;
    const int wm = wave & 1, wn = wave >> 1;
    const int l16 = lane & 15, quad = lane >> 4;

    __shared__ u16 Ahs[2][128][STR];
    __shared__ u16 Bhs[2][128][STR];

    const int ar0 = t >> 2, ak = (t & 3) * 8, ar1 = ar0 + 64;

    f32x4 acc[4][4];
#pragma unroll
    for (int i = 0; i < 4; ++i)
#pragma unroll
        for (int j = 0; j < 4; ++j) acc[i][j] = (f32x4){0.f, 0.f, 0.f, 0.f};

    bf16x8 cur[4];
#define O_LOAD(dst, kk)                                                         \
    do {                                                                        \
        dst[0] = *(const bf16x8*)(Cb  + (size_t)(m0 + ar0) * EMB + (kk) + ak);  \
        dst[1] = *(const bf16x8*)(Cb  + (size_t)(m0 + ar1) * EMB + (kk) + ak);  \
        dst[2] = *(const bf16x8*)(Woh + (size_t)(n0 + ar0) * EMB + (kk) + ak);  \
        dst[3] = *(const bf16x8*)(Woh + (size_t)(n0 + ar1) * EMB + (kk) + ak);  \
    } while (0)

    O_LOAD(cur, 0);
    *(bf16x8*)&Ahs[0][ar0][ak] = cur[0];  *(bf16x8*)&Ahs[0][ar1][ak] = cur[1];
    *(bf16x8*)&Bhs[0][ar0][ak] = cur[2];  *(bf16x8*)&Bhs[0][ar1][ak] = cur[3];

    for (int k0 = 0; k0 < EMB; k0 += 32) {
        const int buf = (k0 >> 5) & 1;
        __syncthreads();
        const int kn = (k0 + 32 < EMB) ? k0 + 32 : 0;
        O_LOAD(cur, kn);

        bf16x8 B4[4];
#pragma unroll
        for (int j = 0; j < 4; ++j)
            B4[j] = *(const bf16x8*)&Bhs[buf][wn * 64 + 16 * j + l16][quad * 8];
#pragma unroll
        for (int i = 0; i < 4; ++i) {
            bf16x8 Ai = *(const bf16x8*)&Ahs[buf][wm * 64 + 16 * i + l16][quad * 8];
#pragma unroll
            for (int j = 0; j < 4; ++j)
                acc[i][j] = __builtin_amdgcn_mfma_f32_16x16x32_bf16(Ai, B4[j], acc[i][j], 0, 0, 0);
        }
        *(bf16x8*)&Ahs[buf ^ 1][ar0][ak] = cur[0];
        *(bf16x8*)&Ahs[buf ^ 1][ar1][ak] = cur[1];
        *(bf16x8*)&Bhs[buf ^ 1][ar0][ak] = cur[2];
        *(bf16x8*)&Bhs[buf ^ 1][ar1][ak] = cur[3];
    }
#undef O_LOAD

#pragma unroll
    for (int i = 0; i < 4; ++i)
#pragma unroll
        for (int r = 0; r < 4; ++r) {
            int m = m0 + wm * 64 + 16 * i + quad * 4 + r;
#pragma unroll
            for (int j = 0; j < 4; ++j) {
                int n = n0 + wn * 64 + 16 * j + l16;
                Y[(size_t)m * EMB + n] = acc[i][j][r] + X[(size_t)m * EMB + n];
            }
        }
}

// ---------------------------------------------------------------------------
// Workspace map (u16 units, 32M total = 64 MiB):
//   [0]   Qh 4M   [4M] Ql   [8M] Kh   [12M] Kl   [16M] Vt
//   [20M] Xh 4M   (-> Cb after qkv_v)
//   [24M] Xl 4M   (-> Woh after qkv_z01, written by prep2)
//   [28M] Wtq_h 1M (-> Wvt after qkv_z01, written by prep2), Wtq_l, Wtk_h, Wtk_l
// ---------------------------------------------------------------------------
extern "C" void kernel_launch(void* const* d_in, const int* in_sizes, int n_in,
                              void* d_out, int out_size, void* d_ws,
                              size_t ws_size, hipStream_t stream)
{
    const float* x  = (const float*)d_in[0];
    const float* Wq = (const float*)d_in[1];
    const float* Wk = (const float*)d_in[2];
    const float* Wv = (const float*)d_in[3];
    const float* Wo = (const float*)d_in[4];
    float* Y = (float*)d_out;

    const size_t NPER = (size_t)MROWS * EMB;   // 4,194,304
    u16* base  = (u16*)d_ws;
    u16* Qh    = base;
    u16* Ql    = Qh + NPER;
    u16* Kh    = Ql + NPER;
    u16* Kl    = Kh + NPER;
    u16* Vt    = Kl + NPER;
    u16* Xh    = Vt + NPER;
    u16* Xl    = Xh + NPER;
    u16* Wtq_h = Xl + NPER;
    u16* Wtq_l = Wtq_h + EMB * EMB;
    u16* Wtk_h = Wtq_l + EMB * EMB;
    u16* Wtk_l = Wtk_h + EMB * EMB;
    u16* Wvt   = Wtq_h;   // alias: Wtq dead after qkv_z01
    u16* Cb    = Xh;      // alias: Xh dead after qkv_v
    u16* Woh   = Xl;      // alias: Xl dead after qkv_z01

    prep1<<<dim3(3072), 256, 0, stream>>>(x, Wq, Wk, Xh, Xl,
                                          Wtq_h, Wtq_l, Wtk_h, Wtk_l);
    qkv_z01<<<dim3(32, 8, 2), 256, 0, stream>>>(Xh, Xl, Wtq_h, Wtq_l,
                                                Wtk_h, Wtk_l, Qh, Ql, Kh, Kl);
    prep2<<<dim3(1024), 256, 0, stream>>>(Wv, Wo, Wvt, Woh);
    qkv_v<<<dim3(32, 8), 256, 0, stream>>>(Xh, Wvt, Vt);
    attn_mfma<<<dim3(SEQ / 128, BATCH * HEADS), 256, 0, stream>>>(Qh, Ql, Kh, Kl,
                                                                  Vt, Cb);
    oproj_mfma<<<dim3(32, 8), 256, 0, stream>>>(Cb, Woh, x, Y);
}